// Round 11
// baseline (113.800 us; speedup 1.0000x reference)
//
#include <hip/hip_runtime.h>

#define N_ROWS  8192
#define DIM     128
#define BM      256
#define NPAN    (N_ROWS / BM)            // 32 panels
#define NTRI    (NPAN * (NPAN + 1) / 2)  // 528 blocks
#define NPH     8                        // K=16 phases

// Fragment-major blob: per 256-row panel (128KB):
//   phase p (K=16, 16KB) -> g32 group (32 rows, 2KB) -> {hi 1KB, lo 1KB}
//   slot l*16B: l = (row&31) + ksub*32, data = 8 fp16 of k = p*16+ksub*8..+8
// Wave MFMA fragment read = base + lane*16 (1KB sequential, conflict-free);
// global_load_lds fill is linear identity copy.
#define BLOB_PER_RB   131072
#define BLOB_PER_PH   16384

typedef _Float16 half8 __attribute__((ext_vector_type(8)));
typedef float    f32x16 __attribute__((ext_vector_type(16)));

typedef const __attribute__((address_space(1))) unsigned int glb_uint;
typedef __attribute__((address_space(3))) unsigned int lds_uint;

__device__ inline void gload_lds16(const void* g, void* l)
{
    __builtin_amdgcn_global_load_lds((glb_uint*)(uintptr_t)g,
                                     (lds_uint*)(uintptr_t)l, 16, 0, 0);
}

// ---------------------------------------------------------------------------
// Prep: X fp32 -> fragment-major fp16-split blob + row norms.
// t = row*16 + kq (kq = 16B k-group 0..15); p = kq>>1, ksub = kq&1.
__global__ __launch_bounds__(256)
void prep_tiled(const float* __restrict__ X, char* __restrict__ blob,
                float* __restrict__ norms)
{
    const int t   = blockIdx.x * 256 + threadIdx.x;  // 0 .. 131071
    const int kq  = t & 15;
    const int p   = kq >> 1;
    const int ks  = kq & 1;
    const int row = t >> 4;

    const float4* src = (const float4*)(X + (size_t)row * DIM + kq * 8);
    const float4 v0 = src[0], v1 = src[1];
    const float xs[8] = {v0.x, v0.y, v0.z, v0.w, v1.x, v1.y, v1.z, v1.w};

    half8 h, l;
    float ns = 0.0f;
    #pragma unroll
    for (int i = 0; i < 8; ++i) {
        const float x = xs[i];
        const _Float16 hh = (_Float16)x;
        h[i] = hh;
        l[i] = (_Float16)(x - (float)hh);
        ns = fmaf(x, x, ns);
    }

    const int rb   = row >> 8;
    const int r    = row & 255;
    const int g32  = r >> 5;
    const int slot = (r & 31) + ks * 32;
    char* base = blob + (size_t)rb * BLOB_PER_RB + p * BLOB_PER_PH
               + g32 * 2048 + slot * 16;
    *(half8*)(base)        = h;   // hi frag
    *(half8*)(base + 1024) = l;   // lo frag

    // 16 consecutive threads cover one row
    #pragma unroll
    for (int off = 1; off <= 8; off <<= 1) ns += __shfl_xor(ns, off);
    if ((t & 15) == 0) norms[row] = ns;
}

// ---------------------------------------------------------------------------
// Main: one 512-thread block per upper-triangle 256x256 tile. 8 waves in a
// 2x4 grid (wave tile 128x64). Double-buffered K=16 phases with prefetch
// (STAGE(p+1) issued before compute(p), single vmcnt(0)+barrier per phase).
__global__ __launch_bounds__(512, 2)
void pairsum_mfma(const char* __restrict__ blob, const float* __restrict__ norms,
                  const int* __restrict__ Y, double* __restrict__ gsum)
{
    // triangular decode over 32 panels: cum(b) = b*(65-b)/2
    const int kb = blockIdx.x;
    int bi = (int)((65.0f - sqrtf(fmaf(-8.0f, (float)kb, 65.0f * 65.0f))) * 0.5f);
    while ((bi + 1) * (65 - (bi + 1)) / 2 <= kb) ++bi;
    while (bi * (65 - bi) / 2 > kb) --bi;
    const int bj = bi + (kb - bi * (65 - bi) / 2);
    const int i0 = bi * BM, j0 = bj * BM;

    const int tid  = threadIdx.x;
    const int lane = tid & 63;
    const int w    = tid >> 6;        // wave 0..7
    const int wy   = w >> 2;          // 2 rows of waves (128 rows each)
    const int wx   = w & 3;           // 4 cols of waves (64 cols each)
    const int lr   = lane & 31;
    const int lh   = lane >> 5;

    // LDS: 2 buffers x (A 16KB + B 16KB) = 64KB
    __shared__ __align__(16) char tile[65536];
    __shared__ float nI[BM], nJ[BM];
    __shared__ int   yI[BM], yJ[BM];
    __shared__ double wsum[8];

    if (tid < BM) { nI[tid] = norms[i0 + tid]; yI[tid] = Y[i0 + tid]; }
    else { const int r = tid - BM; nJ[r] = norms[j0 + r]; yJ[r] = Y[j0 + r]; }
    __syncthreads();

    const char* Apan = blob + (size_t)bi * BLOB_PER_RB;
    const char* Bpan = blob + (size_t)bj * BLOB_PER_RB;

    // 4 async 16B loads per thread per phase (A 16KB + B 16KB over 512 thr)
    auto STAGE = [&](int p, int s) {
        #pragma unroll
        for (int r = 0; r < 2; ++r) {
            gload_lds16(Apan + p * BLOB_PER_PH + r * 8192 + tid * 16,
                        tile + s * 32768 + r * 8192 + tid * 16);
            gload_lds16(Bpan + p * BLOB_PER_PH + r * 8192 + tid * 16,
                        tile + s * 32768 + 16384 + r * 8192 + tid * 16);
        }
    };

    f32x16 acc[4][2];
    #pragma unroll
    for (int m = 0; m < 4; ++m)
        #pragma unroll
        for (int n = 0; n < 2; ++n)
            #pragma unroll
            for (int r = 0; r < 16; ++r)
                acc[m][n][r] = 0.0f;

    STAGE(0, 0);
    asm volatile("s_waitcnt vmcnt(0)" ::: "memory");
    __builtin_amdgcn_s_barrier();
    __builtin_amdgcn_sched_barrier(0);

    #pragma unroll
    for (int p = 0; p < NPH; ++p) {
        if (p + 1 < NPH) STAGE(p + 1, (p + 1) & 1);   // prefetch next phase

        const char* Ab = tile + (p & 1) * 32768;
        const char* Bb = Ab + 16384;
        half8 ah[4], al[4], bh[2], bl[2];
        #pragma unroll
        for (int m = 0; m < 4; ++m) {
            const int ga = (wy * 4 + m) * 2048 + lane * 16;
            ah[m] = *(const half8*)(Ab + ga);
            al[m] = *(const half8*)(Ab + ga + 1024);
        }
        #pragma unroll
        for (int n = 0; n < 2; ++n) {
            const int gb = (wx * 2 + n) * 2048 + lane * 16;
            bh[n] = *(const half8*)(Bb + gb);
            bl[n] = *(const half8*)(Bb + gb + 1024);
        }
        #pragma unroll
        for (int m = 0; m < 4; ++m)
            #pragma unroll
            for (int n = 0; n < 2; ++n) {
                acc[m][n] = __builtin_amdgcn_mfma_f32_32x32x16_f16(ah[m], bh[n], acc[m][n], 0, 0, 0);
                acc[m][n] = __builtin_amdgcn_mfma_f32_32x32x16_f16(ah[m], bl[n], acc[m][n], 0, 0, 0);
                acc[m][n] = __builtin_amdgcn_mfma_f32_32x32x16_f16(al[m], bh[n], acc[m][n], 0, 0, 0);
            }

        // prefetch landed + all reads of this buffer done -> safe to swap
        asm volatile("s_waitcnt vmcnt(0) lgkmcnt(0)" ::: "memory");
        __builtin_amdgcn_sched_barrier(0);
        __builtin_amdgcn_s_barrier();
    }

    // epilogue: C/D map col=lane&31, row=(reg&3)+8*(reg>>2)+4*(lane>>5)
    float s = 0.0f;
    float nJv[2]; int yJv[2];
    #pragma unroll
    for (int n = 0; n < 2; ++n) {
        const int lj = wx * 64 + n * 32 + lr;
        nJv[n] = nJ[lj]; yJv[n] = yJ[lj];
    }
    #pragma unroll
    for (int m = 0; m < 4; ++m) {
        #pragma unroll
        for (int r = 0; r < 16; ++r) {
            const int rowin = (r & 3) + 8 * (r >> 2) + 4 * lh;
            const int li = wy * 128 + m * 32 + rowin;
            const float ni = nI[li];
            const int   yi = yI[li];
            const int   gi = i0 + li;
            #pragma unroll
            for (int n = 0; n < 2; ++n) {
                const int gj = j0 + wx * 64 + n * 32 + lr;
                float sq = fmaf(-2.0f, acc[m][n][r], ni + nJv[n]);
                sq = fmaxf(sq, 0.0f);
                const float d = __builtin_amdgcn_sqrtf(sq);
                if (gi < gj) s = fmaf((yi == yJv[n]) ? 1.0f : -0.5f, d, s);
            }
        }
    }

    #pragma unroll
    for (int off = 32; off > 0; off >>= 1) s += __shfl_down(s, off);
    if (lane == 0) wsum[w] = (double)s;
    __syncthreads();
    if (tid == 0) {
        double t2 = 0.0;
        #pragma unroll
        for (int q = 0; q < 8; ++q) t2 += wsum[q];
        atomicAdd(gsum, t2);
    }
}

__global__ void finalize_kernel(const double* __restrict__ gsum, float* __restrict__ out)
{
    out[0] = (float)(2.0 * gsum[0]);
}

// ---------------------------------------------------------------------------
// Fallback (ws too small): round-1 VALU kernel, known-correct (128 tiles).
#define FBM 128
#define LDSPAD 4
#define LDB (FBM + LDSPAD)
__global__ __launch_bounds__(256)
void pairsum_valu(const float* __restrict__ X, const int* __restrict__ Y,
                  double* __restrict__ gsum)
{
    const int bj = blockIdx.x, bi = blockIdx.y;
    if (bi > bj) return;
    const int tid = threadIdx.x;
    const int i0 = bi * FBM, j0 = bj * FBM;
    __shared__ float As[32][LDB], Bs[32][LDB];
    __shared__ float nI[FBM], nJ[FBM];
    __shared__ int yI[FBM], yJ[FBM];
    __shared__ double wsum[4];
    {
        const int r = tid & (FBM - 1);
        const bool isJ = tid >= FBM;
        const int row = (isJ ? j0 : i0) + r;
        const float4* p = (const float4*)(X + (size_t)row * DIM);
        float s = 0.f;
        #pragma unroll
        for (int q = 0; q < DIM / 4; ++q) {
            float4 v = p[q];
            s = fmaf(v.x, v.x, s); s = fmaf(v.y, v.y, s);
            s = fmaf(v.z, v.z, s); s = fmaf(v.w, v.w, s);
        }
        if (isJ) { nJ[r] = s; yJ[r] = Y[row]; }
        else     { nI[r] = s; yI[r] = Y[row]; }
    }
    float dot[8][8];
    #pragma unroll
    for (int m = 0; m < 8; ++m)
        #pragma unroll
        for (int n = 0; n < 8; ++n) dot[m][n] = 0.f;
    const int tx = tid & 15, ty = tid >> 4;
    for (int kc = 0; kc < DIM; kc += 32) {
        __syncthreads();
        #pragma unroll
        for (int p = 0; p < 4; ++p) {
            const int s2 = p * 256 + tid;
            const int row = s2 >> 3, kg = s2 & 7;
            const float4 va = *(const float4*)(X + (size_t)(i0 + row) * DIM + kc + kg * 4);
            const float4 vb = *(const float4*)(X + (size_t)(j0 + row) * DIM + kc + kg * 4);
            As[kg*4+0][row] = va.x; As[kg*4+1][row] = va.y;
            As[kg*4+2][row] = va.z; As[kg*4+3][row] = va.w;
            Bs[kg*4+0][row] = vb.x; Bs[kg*4+1][row] = vb.y;
            Bs[kg*4+2][row] = vb.z; Bs[kg*4+3][row] = vb.w;
        }
        __syncthreads();
        #pragma unroll
        for (int k = 0; k < 32; ++k) {
            float a[8], b[8];
            *(float4*)&a[0] = *(const float4*)&As[k][ty*8];
            *(float4*)&a[4] = *(const float4*)&As[k][ty*8+4];
            *(float4*)&b[0] = *(const float4*)&Bs[k][tx*8];
            *(float4*)&b[4] = *(const float4*)&Bs[k][tx*8+4];
            #pragma unroll
            for (int m = 0; m < 8; ++m)
                #pragma unroll
                for (int n = 0; n < 8; ++n)
                    dot[m][n] = fmaf(a[m], b[n], dot[m][n]);
        }
    }
    float s = 0.f;
    const int ib = ty * 8, jb = tx * 8;
    #pragma unroll
    for (int m = 0; m < 8; ++m) {
        const int gi = i0 + ib + m;
        const float ni = nI[ib + m];
        const int yi = yI[ib + m];
        #pragma unroll
        for (int n = 0; n < 8; ++n) {
            const int gj = j0 + jb + n;
            float sq = fmaf(-2.f, dot[m][n], ni + nJ[jb + n]);
            sq = fmaxf(sq, 0.f);
            const float d = __builtin_amdgcn_sqrtf(sq);
            if (gi < gj) s = fmaf((yi == yJ[jb + n]) ? 1.0f : -0.5f, d, s);
        }
    }
    #pragma unroll
    for (int off = 32; off > 0; off >>= 1) s += __shfl_down(s, off);
    const int lane = tid & 63, wid = tid >> 6;
    if (lane == 0) wsum[wid] = (double)s;
    __syncthreads();
    if (tid == 0) atomicAdd(gsum, wsum[0] + wsum[1] + wsum[2] + wsum[3]);
}

// ---------------------------------------------------------------------------
extern "C" void kernel_launch(void* const* d_in, const int* in_sizes, int n_in,
                              void* d_out, int out_size, void* d_ws, size_t ws_size,
                              hipStream_t stream)
{
    const float* X = (const float*)d_in[0];
    const int*   Y = (const int*)d_in[1];
    float* out = (float*)d_out;

    // ws layout: [0] double gsum | 64: blob 4MB | +4MB: norms 32KB
    const size_t OFF_BLOB = 64;
    const size_t OFF_NORM = OFF_BLOB + (size_t)NPAN * BLOB_PER_RB;
    const size_t REQ      = OFF_NORM + (size_t)N_ROWS * 4;

    double* gsum = (double*)d_ws;
    hipMemsetAsync(d_ws, 0, sizeof(double), stream);

    if (ws_size >= REQ) {
        char*  blob  = (char*)d_ws + OFF_BLOB;
        float* norms = (float*)((char*)d_ws + OFF_NORM);
        prep_tiled<<<(N_ROWS * 16) / 256, 256, 0, stream>>>(X, blob, norms);
        pairsum_mfma<<<NTRI, 512, 0, stream>>>(blob, norms, Y, gsum);
    } else {
        dim3 grid(N_ROWS / FBM, N_ROWS / FBM);
        pairsum_valu<<<grid, 256, 0, stream>>>(X, Y, gsum);
    }
    finalize_kernel<<<1, 1, 0, stream>>>(gsum, out);
}